// Round 7
// baseline (440.532 us; speedup 1.0000x reference)
//
#include <hip/hip_runtime.h>

// GumbelVQ — fused 2-pass streaming (pass1 = logits+softmax+argmax+q-accum).
// Outputs (concatenated float32 in d_out):
//   [0 .. 8388607]      quantized  [16,16384,32]
//   [8388608]           commitment_loss (scalar)
//   [8388609 .. 8650752] indices   [16,16384] (stored as float)
//   [8650753]           perplexity (scalar)
//
// ws float layout:
//   [0..255]    avg_probs accumulator
//   [256]       loss accumulator
//   [257..512]  ||e_k||^2
//   [1024 .. 1024+M)  invS per row
//   floats from 1024+M : p (unnormalized numerators) bf16 [M][256]
//
// Round-7: fuse pass2's q = sum_k p_k e_k into pass1. Rationale: gfx9 scalar
// loads complete out-of-order -> every use forces lgkmcnt(0) draining ALL
// outstanding s_loads, so per-code compute must exceed the ~200cy s_load
// latency for 1-ahead prefetch to hide it. Dot alone = 64 cy (42% VALUBusy
// in r6); dot+q-accum on the SAME e-row SGPRs = ~150 cy -> latency covered
// even at ~2 waves/SIMD (VGPR ~105 cuts residency per the empirical
// waves/CU ~ 768/VGPR law). Also removes pass2's ~110us wall + 162 MB.

#define M_ROWS  262144
#define OUT_LOSS 8388608
#define OUT_IDX  8388609
#define OUT_PPL  8650753

__device__ __forceinline__ unsigned int f2bf_u(float f) {
  unsigned int u = __float_as_uint(f);
  u += 0x7fffu + ((u >> 16) & 1u);
  return u >> 16;
}
__device__ __forceinline__ float bf2f(unsigned int lo16) {
  return __uint_as_float(lo16 << 16);
}

__global__ __launch_bounds__(256) void vq_prep(const float* __restrict__ emb,
                                               float* __restrict__ ws) {
  int t = threadIdx.x;
  ws[t] = 0.0f;                 // avg accumulators
  if (t == 0) ws[256] = 0.0f;   // loss accumulator
  const float4* e4 = (const float4*)emb;
  float s = 0.0f;
#pragma unroll
  for (int j = 0; j < 8; ++j) {
    float4 v = e4[t * 8 + j];
    s += v.x * v.x + v.y * v.y + v.z * v.z + v.w * v.w;
  }
  ws[257 + t] = s;
}

// ---- fused pass 1: logits, p(bf16)->ws, invS, argmax, loss, quantized -------
// 2048 blocks x 256 thr; block owns 128 rows; half = tid>>7 owns 128 codes.
__global__ __launch_bounds__(256, 2) void vq_pass1(
    const float* __restrict__ x_in, const float* __restrict__ emb,
    const float* __restrict__ gum, const float* __restrict__ ne,
    float* __restrict__ invS_ws, unsigned short* __restrict__ p_ws,
    float* __restrict__ loss_ws, float* __restrict__ out) {
  __shared__ float shq[128][33];            // half1 -> half0 q handoff (pad 33)
  __shared__ float sh_ssum[128];
  __shared__ float sh_tmax[128];
  __shared__ int   sh_imax[128];

  const int tid  = threadIdx.x;
  const int lane = tid & 63;
  const int rloc = tid & 127;
  const int half = tid >> 7;
  // wave-uniform; readfirstlane keeps the code index on the scalar path (r6).
  const int kbase = __builtin_amdgcn_readfirstlane(half * 128);
  const int row  = blockIdx.x * 128 + rloc;

  float xr[32];
  {
    const float4* xv = (const float4*)(x_in + (size_t)row * 32);
#pragma unroll
    for (int j = 0; j < 8; ++j) {
      float4 v = xv[j];
      xr[4*j+0] = v.x; xr[4*j+1] = v.y; xr[4*j+2] = v.z; xr[4*j+3] = v.w;
    }
  }

  float q[32];
#pragma unroll
  for (int d = 0; d < 32; ++d) q[d] = 0.0f;

  const float4* g4 = (const float4*)(gum + (size_t)row * 256 + kbase);
  const float4* e4 = (const float4*)emb;
  uint4* pout = (uint4*)(p_ws + (size_t)row * 256 + kbase);

  float ssum = 0.0f;
  float tmax = -3.0e38f;
  int   imax = 0;

  unsigned int packs[16];                   // 32 codes of bf16 p (64B store)

  for (int kg = 0; kg < 8; ++kg) {          // 8 groups of 16 codes
    // 16 gumbel uniforms = one FULL 64B line, consumed immediately
    float uv[16];
#pragma unroll
    for (int j = 0; j < 4; ++j) {
      float4 v = g4[kg * 4 + j];
      uv[4*j+0] = v.x; uv[4*j+1] = v.y; uv[4*j+2] = v.z; uv[4*j+3] = v.w;
    }
#pragma unroll
    for (int kk = 0; kk < 16; ++kk) {
      const int k = kbase + kg * 16 + kk;   // scalar (SGPR + consts)
      // e-row: uniform -> s_load into SGPRs; shared by dot AND q loops
      float4 er[8];
#pragma unroll
      for (int jj = 0; jj < 8; ++jj) er[jj] = e4[k * 8 + jj];

      const float g = -__logf(-__logf(uv[kk] + 1e-20f) + 1e-20f);
      float d0 = 0.f, d1 = 0.f, d2 = 0.f, d3 = 0.f;
#pragma unroll
      for (int jj = 0; jj < 8; ++jj) {
        d0 = fmaf(xr[4*jj+0], er[jj].x, d0);
        d1 = fmaf(xr[4*jj+1], er[jj].y, d1);
        d2 = fmaf(xr[4*jj+2], er[jj].z, d2);
        d3 = fmaf(xr[4*jj+3], er[jj].w, d3);
      }
      const float dot = (d0 + d1) + (d2 + d3);
      const float t = fmaf(2.0f, dot, g) - ne[k];  // ||x||^2 const per row
      const float p = __expf(t);
      ssum += p;
      if (t > tmax) { tmax = t; imax = k; }
      // q-accumulation on the SAME er SGPRs (the fused second GEMM)
#pragma unroll
      for (int jj = 0; jj < 8; ++jj) {
        q[4*jj+0] = fmaf(p, er[jj].x, q[4*jj+0]);
        q[4*jj+1] = fmaf(p, er[jj].y, q[4*jj+1]);
        q[4*jj+2] = fmaf(p, er[jj].z, q[4*jj+2]);
        q[4*jj+3] = fmaf(p, er[jj].w, q[4*jj+3]);
      }
      const int idx32 = ((kg & 1) << 4) + kk;
      if (idx32 & 1) packs[idx32 >> 1] |= f2bf_u(p) << 16;
      else           packs[idx32 >> 1]  = f2bf_u(p);
    }
    if (kg & 1) {                           // full 64B line of p per 2 groups
      const uint4* pd = (const uint4*)packs;
#pragma unroll
      for (int j = 0; j < 4; ++j) pout[(kg >> 1) * 4 + j] = pd[j];
    }
  }

  if (half == 1) {
    sh_ssum[rloc] = ssum; sh_tmax[rloc] = tmax; sh_imax[rloc] = imax;
#pragma unroll
    for (int d = 0; d < 32; ++d) shq[rloc][d] = q[d];
  }
  __syncthreads();
  if (half == 0) {
    const float sB = sh_ssum[rloc];
    const float tB = sh_tmax[rloc];
    const int   iB = sh_imax[rloc];
    if (tB > tmax) { tmax = tB; imax = iB; }   // strict > keeps first-index ties
    const float invS = 1.0f / (ssum + sB);
    invS_ws[row] = invS;
    out[OUT_IDX + row] = (float)imax;

    const float tr  = 1.0f / 3.0f;     // (1.0-0.5)/(2.0-0.5)
    const float otr = 1.0f - tr;
    const float4* ehv = (const float4*)(emb + (size_t)imax * 32);
    float4* outq = (float4*)(out + (size_t)row * 32);
    float cl = 0.0f;
#pragma unroll
    for (int j = 0; j < 8; ++j) {
      float4 e = ehv[j];
      float4 o;
      float dx;
      o.x = fmaf(tr, (q[4*j+0] + shq[rloc][4*j+0]) * invS, otr * e.x);
      o.y = fmaf(tr, (q[4*j+1] + shq[rloc][4*j+1]) * invS, otr * e.y);
      o.z = fmaf(tr, (q[4*j+2] + shq[rloc][4*j+2]) * invS, otr * e.z);
      o.w = fmaf(tr, (q[4*j+3] + shq[rloc][4*j+3]) * invS, otr * e.w);
      outq[j] = o;
      dx = e.x - xr[4*j+0]; cl = fmaf(dx, dx, cl);
      dx = e.y - xr[4*j+1]; cl = fmaf(dx, dx, cl);
      dx = e.z - xr[4*j+2]; cl = fmaf(dx, dx, cl);
      dx = e.w - xr[4*j+3]; cl = fmaf(dx, dx, cl);
    }
#pragma unroll
    for (int off = 32; off > 0; off >>= 1) cl += __shfl_down(cl, off);
    if (lane == 0) atomicAdd(loss_ws, cl);
  }
}

// ---- pass 2b: avg_probs column sums (coalesced, 8192 waves) -----------------
__global__ __launch_bounds__(256) void vq_avg(
    const unsigned short* __restrict__ p_ws, const float* __restrict__ invS_ws,
    float* __restrict__ avg_ws) {
  __shared__ float sh[256];
  const int tid = threadIdx.x, lane = tid & 63, w = tid >> 6;
  sh[tid] = 0.0f;
  __syncthreads();
  const int base = (blockIdx.x * 4 + w) * 32;   // 8192 waves, 32 rows each
  const float iv = invS_ws[base + (lane & 31)];
  float a0 = 0.f, a1 = 0.f, a2 = 0.f, a3 = 0.f;
#pragma unroll 4
  for (int r = 0; r < 32; ++r) {
    const float s = __shfl(iv, r);
    const unsigned short* pr = p_ws + (size_t)(base + r) * 256;
    a0 = fmaf(bf2f(pr[  0 + lane]), s, a0);
    a1 = fmaf(bf2f(pr[ 64 + lane]), s, a1);
    a2 = fmaf(bf2f(pr[128 + lane]), s, a2);
    a3 = fmaf(bf2f(pr[192 + lane]), s, a3);
  }
  atomicAdd(&sh[  0 + lane], a0);
  atomicAdd(&sh[ 64 + lane], a1);
  atomicAdd(&sh[128 + lane], a2);
  atomicAdd(&sh[192 + lane], a3);
  __syncthreads();
  atomicAdd(&avg_ws[tid], sh[tid]);
}

__global__ __launch_bounds__(256) void vq_fin(const float* __restrict__ ws,
                                              float* __restrict__ out) {
  __shared__ float red[256];
  int t = threadIdx.x;
  float avg = ws[t] * (1.0f / 262144.0f);
  red[t] = -avg * __logf(avg + 1e-10f);
  __syncthreads();
  for (int s = 128; s > 0; s >>= 1) {
    if (t < s) red[t] += red[t + s];
    __syncthreads();
  }
  if (t == 0) {
    out[OUT_PPL]  = __expf(red[0]);
    out[OUT_LOSS] = ws[256] * (1.0f / 8388608.0f);
  }
}

// ---- fallback (round-1 monolithic, if ws too small) -------------------------
__global__ __launch_bounds__(256, 1) void vq_main(
    const float* __restrict__ x_in, const float* __restrict__ emb,
    const float* __restrict__ gum, const float* __restrict__ ne,
    float* __restrict__ avg_ws, float* __restrict__ loss_ws,
    float* __restrict__ out) {
  extern __shared__ unsigned char dynsmem[];
  unsigned short* p_lds = (unsigned short*)dynsmem;

  const int tid  = threadIdx.x;
  const int lane = tid & 63;
  const int w    = tid >> 6;
  const int row  = blockIdx.x * 256 + tid;
  unsigned short* my_p = p_lds + (size_t)(w * 64 + lane) * 258;

  float xr[32];
  {
    const float4* xv = (const float4*)(x_in + (size_t)row * 32);
#pragma unroll
    for (int j = 0; j < 8; ++j) {
      float4 v = xv[j];
      xr[4*j+0] = v.x; xr[4*j+1] = v.y; xr[4*j+2] = v.z; xr[4*j+3] = v.w;
    }
  }
  float q[32];
#pragma unroll
  for (int d = 0; d < 32; ++d) q[d] = 0.0f;

  float ssum = 0.0f;
  float tmax = -3.0e38f;
  int   imax = 0;

  const float4* g4 = (const float4*)(gum + (size_t)row * 256);
  const float4* e4 = (const float4*)emb;

  for (int kg = 0; kg < 8; ++kg) {
    float uv[32];
#pragma unroll
    for (int j = 0; j < 8; ++j) {
      float4 v = g4[kg * 8 + j];
      uv[4*j+0] = v.x; uv[4*j+1] = v.y; uv[4*j+2] = v.z; uv[4*j+3] = v.w;
    }
#pragma unroll
    for (int kk = 0; kk < 32; ++kk) {
      const int k = kg * 32 + kk;
      float er[32];
#pragma unroll
      for (int j = 0; j < 8; ++j) {
        float4 v = e4[k * 8 + j];
        er[4*j+0] = v.x; er[4*j+1] = v.y; er[4*j+2] = v.z; er[4*j+3] = v.w;
      }
      float d0 = 0.f, d1 = 0.f, d2 = 0.f, d3 = 0.f;
#pragma unroll
      for (int d = 0; d < 32; d += 4) {
        d0 = fmaf(xr[d+0], er[d+0], d0);
        d1 = fmaf(xr[d+1], er[d+1], d1);
        d2 = fmaf(xr[d+2], er[d+2], d2);
        d3 = fmaf(xr[d+3], er[d+3], d3);
      }
      const float dot = (d0 + d1) + (d2 + d3);
      const float inner = -__logf(uv[kk] + 1e-20f);
      const float g = -__logf(inner + 1e-20f);
      const float t = fmaf(2.0f, dot, g) - ne[k];
      const float p = __expf(t);
      ssum += p;
      if (t > tmax) { tmax = t; imax = k; }
#pragma unroll
      for (int d = 0; d < 32; ++d) q[d] = fmaf(p, er[d], q[d]);
      my_p[k] = (unsigned short)f2bf_u(p);
    }
  }

  const float invS = 1.0f / ssum;
  {
    const float tr  = 1.0f / 3.0f;
    const float otr = 1.0f - tr;
    const float4* ehv = (const float4*)(emb + (size_t)imax * 32);
    float4* outq = (float4*)(out + (size_t)row * 32);
    float cl = 0.0f;
#pragma unroll
    for (int j = 0; j < 8; ++j) {
      float4 e = ehv[j];
      float4 o;
      float qs, dx;
      qs = q[4*j+0]*invS; o.x = tr*qs + otr*e.x; dx = e.x - xr[4*j+0]; cl = fmaf(dx,dx,cl);
      qs = q[4*j+1]*invS; o.y = tr*qs + otr*e.y; dx = e.y - xr[4*j+1]; cl = fmaf(dx,dx,cl);
      qs = q[4*j+2]*invS; o.z = tr*qs + otr*e.z; dx = e.z - xr[4*j+2]; cl = fmaf(dx,dx,cl);
      qs = q[4*j+3]*invS; o.w = tr*qs + otr*e.w; dx = e.w - xr[4*j+3]; cl = fmaf(dx,dx,cl);
      outq[j] = o;
    }
    out[OUT_IDX + row] = (float)imax;
#pragma unroll
    for (int off = 32; off > 0; off >>= 1) cl += __shfl_down(cl, off);
    if (lane == 0) atomicAdd(loss_ws, cl);
  }

  __syncthreads();

  float a0 = 0.f, a1 = 0.f, a2 = 0.f, a3 = 0.f;
  for (int r = 0; r < 64; ++r) {
    const float invS_r = __shfl(invS, r);
    const unsigned short* rp = p_lds + (size_t)(w * 64 + r) * 258;
    a0 = fmaf(bf2f(rp[  0 + lane]), invS_r, a0);
    a1 = fmaf(bf2f(rp[ 64 + lane]), invS_r, a1);
    a2 = fmaf(bf2f(rp[128 + lane]), invS_r, a2);
    a3 = fmaf(bf2f(rp[192 + lane]), invS_r, a3);
  }
  atomicAdd(&avg_ws[  0 + lane], a0);
  atomicAdd(&avg_ws[ 64 + lane], a1);
  atomicAdd(&avg_ws[128 + lane], a2);
  atomicAdd(&avg_ws[192 + lane], a3);
}

extern "C" void kernel_launch(void* const* d_in, const int* in_sizes, int n_in,
                              void* d_out, int out_size, void* d_ws, size_t ws_size,
                              hipStream_t stream) {
  const float* x   = (const float*)d_in[0];
  const float* emb = (const float*)d_in[1];
  const float* gum = (const float*)d_in[2];
  float* out = (float*)d_out;
  float* ws  = (float*)d_ws;

  (void)in_sizes; (void)n_in; (void)out_size;

  vq_prep<<<1, 256, 0, stream>>>(emb, ws);

  const size_t need = (size_t)(1024 + M_ROWS) * 4 + (size_t)M_ROWS * 256 * 2;
  if (ws_size >= need) {
    float* invS = ws + 1024;
    unsigned short* p = (unsigned short*)(ws + 1024 + M_ROWS);
    vq_pass1<<<2048, 256, 0, stream>>>(x, emb, gum, ws + 257, invS, p, ws + 256, out);
    vq_avg<<<2048, 256, 0, stream>>>(p, invS, ws);
  } else {
    hipFuncSetAttribute((const void*)vq_main,
                        hipFuncAttributeMaxDynamicSharedMemorySize, 132128);
    vq_main<<<1024, 256, 132128, stream>>>(x, emb, gum, ws + 257, ws, ws + 256, out);
  }
  vq_fin<<<1, 256, 0, stream>>>(ws, out);
}